// Round 1
// baseline (536.704 us; speedup 1.0000x reference)
//
#include <hip/hip_runtime.h>
#include <hip/hip_bf16.h>

// Problem constants (fixed shapes from the reference)
#define M_ROWS 25088   // 8 * 3136 embedding rows
#define N_CENT 4096    // centroids
#define K_DIM  1536    // feature dim (elements == bytes in fp8)

// GEMM tiling: 256x256 tile, 8 waves (512 thr), per-wave 128x64 output,
// mfma_scale_f32_32x32x64_f8f6f4, BK=64, triple-buffered LDS (96 KB).
#define BM 256
#define BN 256
#define BKT 64
#define NKT (K_DIM / BKT)      // 24 K-tiles
#define REGION_B 16384         // BM*BKT bytes: A region size == B region size
#define TILE_LDS 32768         // one buffer = A region + B region

typedef __attribute__((ext_vector_type(8)))  int   int8v;    // f8f6f4 A/B frag (32 fp8)
typedef __attribute__((ext_vector_type(4)))  int   int4v;
typedef __attribute__((ext_vector_type(16))) float floatx16; // 32x32 MFMA accumulator

typedef __attribute__((address_space(1))) const void gvoid;
typedef __attribute__((address_space(3))) void lvoid;

__device__ __forceinline__ void load_lds16(const void* g, void* l) {
    // async global->LDS, 16B per lane; LDS dest = wave-uniform base + lane*16
    __builtin_amdgcn_global_load_lds((gvoid*)g, (lvoid*)l, 16, 0, 0);
}

// Wave-per-row convert: fp32 -> fp8 e4m3 (OCP, HW cvt) + fp32 sum-of-squares.
// Block = 256 threads = 4 waves = 4 rows; 6 float4 loads/lane; shuffle-only
// reduction. Norms stay exact fp32 so only the dot term carries fp8 noise.
// (unchanged from the 436.5 us session - proven)
__global__ __launch_bounds__(256) void convert_rows(
    const float* __restrict__ src, unsigned int* __restrict__ dst,
    float* __restrict__ norms, unsigned int* __restrict__ minbuf, int nrows)
{
    const int row  = blockIdx.x * 4 + (threadIdx.x >> 6);
    const int lane = threadIdx.x & 63;
    if (row >= nrows) return;

    const float4* s = (const float4*)(src + (size_t)row * K_DIM);
    unsigned int* d = dst + (size_t)row * (K_DIM / 4);

    float4 v[6];
    #pragma unroll
    for (int j = 0; j < 6; ++j) v[j] = s[lane + j * 64];   // 6 loads in flight

    float ssq = 0.f;
    #pragma unroll
    for (int j = 0; j < 6; ++j) {
        ssq += v[j].x * v[j].x + v[j].y * v[j].y + v[j].z * v[j].z + v[j].w * v[j].w;
        int u = __builtin_amdgcn_cvt_pk_fp8_f32(v[j].x, v[j].y, 0, false);
        u     = __builtin_amdgcn_cvt_pk_fp8_f32(v[j].z, v[j].w, u, true);
        d[lane + j * 64] = (unsigned int)u;
    }

    #pragma unroll
    for (int off = 32; off >= 1; off >>= 1) ssq += __shfl_down(ssq, off, 64);
    if (lane == 0) {
        norms[row] = ssq;
        if (minbuf) minbuf[row] = 0x7F800000u;  // +inf bits (ws re-poisoned each launch)
    }
}

// 256x256 MX-fp8 GEMM tile with fused per-row min(dist^2) epilogue.
// A = embeds [M,K] fp8, B = centroids [N,K] fp8 (NT layout).
//
// Structure (T2+T3+T4+T5):
//  - 8 waves as 2(M) x 4(N); wave owns a 128x64 output = 4(im) x 2(in)
//    32x32 accumulator tiles. FLOP per LDS byte read = 85 (vs 64 at the old
//    64x64 wave tile), no wave-pair read duplication.
//  - mfma_scale_f32_32x32x64_f8f6f4: A lane layout row=l&31, k-bytes
//    (l>>5)*32..+31 (analog of the verified 16x16x128 row=l&15 / (l>>4)*32).
//  - Triple-buffered LDS (3 x 32 KB): at K-tile t, stage t+2, compute t,
//    then ONE `s_waitcnt vmcnt(4)` (keeps t+2's 4 loads in flight, forces
//    t+1's landed - per-wave wait before the barrier makes it global) +
//    ONE s_barrier. Prefetch distance ~1.3 tiles > 900-cyc HBM latency.
//    Never vmcnt(0) in steady state (T4).
//  - LDS sigma-swizzle (T2, rule #21 both-sides): physical = logical ^
//    (((logical>>7)&7)<<4) - XOR the 16B-granule index with the row-pair
//    index. global_load_lds keeps a LINEAR dest; the global SOURCE is
//    pre-swizzled per lane; frag reads apply sigma on the address (the two
//    16B halves of a frag sit at p and p^16). Hand-checked histogram: every
//    frag-read instruction puts exactly 8 lanes on each 16B bank-granule ->
//    conflict-free (the 8-phase minimum for a 1 KB wave access).
//
// Hard-won codegen rules kept from the previous session:
//  - `#pragma unroll 1` on the K-loop is MANDATORY (full unroll spills).
//  - Frag construction must be SSA (loads + shufflevector merge).
__global__ __launch_bounds__(512, 2) void gemm_min(
    const unsigned char* __restrict__ A,
    const unsigned char* __restrict__ B,
    const float* __restrict__ nx,
    const float* __restrict__ nc,
    unsigned int* __restrict__ minbuf)
{
    __shared__ __align__(16) unsigned char lds[3 * TILE_LDS];   // 96 KB -> 1 block/CU

    const int tid  = threadIdx.x;
    const int wave = tid >> 6;
    const int lane = tid & 63;
    const int rl   = lane & 31;        // row (A) / col (B) within a 32-tile
    const int h    = lane >> 5;        // k-half selector
    const int wm   = wave >> 2;        // 0..1 : 128-row half of the M-tile
    const int wn   = wave & 3;         // 0..3 : 64-col slice of the N-tile
    const int tile_n = blockIdx.x * BN;
    const int tile_m = blockIdx.y * BM;

    // ---- staging: per-lane sigma-preswizzled global sources -------------
    // Wave w fills physical bytes [w*2048, w*2048+2048) of each region
    // (two 1 KB global_load_lds per operand per tile).
    const int p0 = wave * 2048 + lane * 16;
    const int p1 = p0 + 1024;
    const int a0 = p0 ^ (((p0 >> 7) & 7) << 4);   // logical offset for phys p0
    const int a1 = p1 ^ (((p1 >> 7) & 7) << 4);
    const unsigned char* aSrc0 = A + (size_t)(tile_m + (a0 >> 6)) * K_DIM + (a0 & 63);
    const unsigned char* aSrc1 = A + (size_t)(tile_m + (a1 >> 6)) * K_DIM + (a1 & 63);
    const unsigned char* bSrc0 = B + (size_t)(tile_n + (a0 >> 6)) * K_DIM + (a0 & 63);
    const unsigned char* bSrc1 = B + (size_t)(tile_n + (a1 >> 6)) * K_DIM + (a1 & 63);
    char* ldsW = (char*)lds + wave * 2048;        // wave's dest within a region

    // ---- frag-read physical offsets (sigma applied) ---------------------
    // logical addr = row*64 + h*32 (+16 for the second b128); XOR value
    // x = ((row>>1)&7)<<4 is im/in-independent (tile offsets are mult. of 2048).
    const int x   = ((rl >> 1) & 7) << 4;
    const int pa0 = (((wm * 128 + rl) * 64 + h * 32) ^ x);
    const int pa1 = pa0 ^ 16;
    const int pb0 = (((wn * 64 + rl) * 64 + h * 32) ^ x) + REGION_B;
    const int pb1 = pb0 ^ 16;

    floatx16 acc[4][2];
    #pragma unroll
    for (int im = 0; im < 4; ++im)
        #pragma unroll
        for (int in = 0; in < 2; ++in)
            #pragma unroll
            for (int k = 0; k < 16; ++k) acc[im][in][k] = 0.f;

    // ---- prologue: stage tiles 0 and 1, wait for tile 0 only ------------
    load_lds16(aSrc0, ldsW);
    load_lds16(aSrc1, ldsW + 1024);
    load_lds16(bSrc0, ldsW + REGION_B);
    load_lds16(bSrc1, ldsW + REGION_B + 1024);
    load_lds16(aSrc0 + BKT, ldsW + TILE_LDS);
    load_lds16(aSrc1 + BKT, ldsW + TILE_LDS + 1024);
    load_lds16(bSrc0 + BKT, ldsW + TILE_LDS + REGION_B);
    load_lds16(bSrc1 + BKT, ldsW + TILE_LDS + REGION_B + 1024);
    aSrc0 += 2 * BKT; aSrc1 += 2 * BKT; bSrc0 += 2 * BKT; bSrc1 += 2 * BKT;
    asm volatile("s_waitcnt vmcnt(4)" ::: "memory");   // tile 0 landed; tile 1 in flight
    __builtin_amdgcn_s_barrier();
    __builtin_amdgcn_sched_barrier(0);

    int cur = 0;   // buffer holding tile t
    int stb = 2;   // buffer receiving tile t+2
    #pragma unroll 1   // MUST stay rolled: full unroll (trip=24) spills
    for (int t = 0; t < NKT; ++t) {
        if (t < NKT - 2) {   // stage tile t+2 (issue EARLY, before compute)
            char* db = (char*)lds + stb * TILE_LDS + wave * 2048;
            load_lds16(aSrc0, db);
            load_lds16(aSrc1, db + 1024);
            load_lds16(bSrc0, db + REGION_B);
            load_lds16(bSrc1, db + REGION_B + 1024);
            aSrc0 += BKT; aSrc1 += BKT; bSrc0 += BKT; bSrc1 += BKT;
        }

        const unsigned char* bufp = (const unsigned char*)lds + cur * TILE_LDS;

        int8v a[4];
        #pragma unroll
        for (int im = 0; im < 4; ++im) {
            const int4v lo = *(const int4v*)(bufp + pa0 + im * 2048);
            const int4v hi = *(const int4v*)(bufp + pa1 + im * 2048);
            a[im] = __builtin_shufflevector(lo, hi, 0, 1, 2, 3, 4, 5, 6, 7);
        }

        __builtin_amdgcn_s_setprio(1);
        #pragma unroll
        for (int in = 0; in < 2; ++in) {
            const int4v lo = *(const int4v*)(bufp + pb0 + in * 2048);
            const int4v hi = *(const int4v*)(bufp + pb1 + in * 2048);
            const int8v b = __builtin_shufflevector(lo, hi, 0, 1, 2, 3, 4, 5, 6, 7);
            #pragma unroll
            for (int im = 0; im < 4; ++im)
                acc[im][in] = __builtin_amdgcn_mfma_scale_f32_32x32x64_f8f6f4(
                    a[im], b, acc[im][in],
                    0 /*cbsz: A=e4m3*/, 0 /*blgp: B=e4m3*/,
                    0, 0x7F7F7F7F,   // scale_a opsel, E8M0 1.0 in every byte
                    0, 0x7F7F7F7F);  // scale_b
        }
        __builtin_amdgcn_s_setprio(0);

        if (t < NKT - 1) {
            // Counted wait: allow tile t+2's 4 loads to stay in flight,
            // force tile t+1's 4 to have landed (per-wave; the barrier
            // then makes it hold for all waves). Drain only at the tail.
            if (t < NKT - 2) { asm volatile("s_waitcnt vmcnt(4)" ::: "memory"); }
            else             { asm volatile("s_waitcnt vmcnt(0)" ::: "memory"); }
            __builtin_amdgcn_s_barrier();
            __builtin_amdgcn_sched_barrier(0);
        }
        cur = (cur == 2) ? 0 : cur + 1;
        stb = (stb == 2) ? 0 : stb + 1;
    }

    // ---- epilogue: dist^2 = nx[m] + nc[p] - 2*dot; per-row min ----------
    // 32x32 C/D layout (guide m74/m101, dtype-independent): col = lane&31,
    // row = (reg&3) + 8*(reg>>2) + 4*(lane>>5). A row lives in one 32-lane
    // half; reduce with shfl_xor masks 16..1 (never cross bit5).
    float cn[2];
    #pragma unroll
    for (int in = 0; in < 2; ++in) cn[in] = nc[tile_n + wn * 64 + in * 32 + rl];

    #pragma unroll
    for (int im = 0; im < 4; ++im) {
        #pragma unroll
        for (int r = 0; r < 16; ++r) {
            float v = fminf(cn[0] - 2.f * acc[im][0][r],
                            cn[1] - 2.f * acc[im][1][r]);
            v = fminf(v, __shfl_xor(v, 16, 64));
            v = fminf(v, __shfl_xor(v, 8, 64));
            v = fminf(v, __shfl_xor(v, 4, 64));
            v = fminf(v, __shfl_xor(v, 2, 64));
            v = fminf(v, __shfl_xor(v, 1, 64));
            if (rl == 0) {
                const int row = tile_m + wm * 128 + im * 32
                              + (r & 3) + 8 * (r >> 2) + 4 * h;
                atomicMin(&minbuf[row], __float_as_uint(v + nx[row]));
            }
        }
    }
}

__global__ void finalize_kernel(const unsigned int* __restrict__ minbuf,
                                float* __restrict__ out)
{
    const int i = blockIdx.x * 256 + threadIdx.x;
    if (i == 0) out[0] = 0.0f;                 // loss (eval mode)
    if (i < M_ROWS) out[1 + i] = sqrtf(__uint_as_float(minbuf[i]));
}

extern "C" void kernel_launch(void* const* d_in, const int* in_sizes, int n_in,
                              void* d_out, int out_size, void* d_ws, size_t ws_size,
                              hipStream_t stream)
{
    const float* embeds = (const float*)d_in[0];   // [8, 3136, 1536] fp32
    const float* cents  = (const float*)d_in[1];   // [4096, 1536] fp32
    float* out = (float*)d_out;                    // [1 + 25088] fp32

    char* ws = (char*)d_ws;
    const size_t offA   = 0;                                   // 38,535,168 B (fp8)
    const size_t offB   = offA + (size_t)M_ROWS * K_DIM;       //  6,291,456 B (fp8)
    const size_t offNx  = offB + (size_t)N_CENT * K_DIM;       //    100,352 B
    const size_t offNc  = offNx + (size_t)M_ROWS * 4;          //     16,384 B
    const size_t offMin = offNc + (size_t)N_CENT * 4;          //    100,352 B

    unsigned char* A8 = (unsigned char*)(ws + offA);
    unsigned char* B8 = (unsigned char*)(ws + offB);
    float* nx = (float*)(ws + offNx);
    float* nc = (float*)(ws + offNc);
    unsigned int* minbuf = (unsigned int*)(ws + offMin);

    convert_rows<<<M_ROWS / 4, 256, 0, stream>>>(embeds, (unsigned int*)A8, nx, minbuf, M_ROWS);
    convert_rows<<<N_CENT / 4, 256, 0, stream>>>(cents, (unsigned int*)B8, nc, nullptr, N_CENT);

    dim3 grid(N_CENT / BN, M_ROWS / BM);   // (16, 98); x = column tiles for A-tile L2/LLC reuse
    gemm_min<<<grid, 512, 0, stream>>>(A8, B8, nx, nc, minbuf);

    finalize_kernel<<<(M_ROWS + 255) / 256, 256, 0, stream>>>(minbuf, out);
}